// Round 6
// baseline (16.366 us; speedup 1.0000x reference)
//
#include <hip/hip_runtime.h>
#include <math.h>

// Problem constants (fixed by setup_inputs)
#define B 4
#define H 64
#define W 64
#define C 256
#define R 128
#define PH 7
#define PW 7

#define BLOCKS_TOTAL 6272               // 8 XCD classes x 784
#define PAIRS_PER_BATCH 3136            // 6272 cells / 2

typedef float f32x4 __attribute__((ext_vector_type(4)));

__global__ __launch_bounds__(256) void roi_pool_kernel(
    const float* __restrict__ fm,      // [B,H,W,C]
    const float* __restrict__ rois,    // [B,R,4] = x1,y1,x2,y2
    float* __restrict__ out)           // [B,R,PH,PW,C]
{
    const int wave = threadIdx.x >> 6;
    const int lane = threadIdx.x & 63;
    const int half = lane >> 5;         // which cell of the pair (0/1)
    const int l    = lane & 31;         // channel lane within the half-wave

    // XCD-aware swizzle: blockIdx % 8 = XCD (round-robin dispatch).
    // XCD 2b+chalf serves ONLY channels [chalf*128, chalf*128+128) of batch b
    // -> per-XCD fm working set = 2.0 MiB, resident in the 4 MiB L2.
    const int xcd   = blockIdx.x & 7;
    const int slot  = blockIdx.x >> 3;       // 0..783
    const int b     = xcd >> 1;              // 0..3
    const int chalf = xcd & 1;               // channel half

    const int pair = slot * 4 + wave;        // 0..3135
    const int cell_in_b = pair * 2 + half;   // 0..6271, per-lane (per half-wave)

    // decode (r, p, q) from cell_in_b, row-major [R,PH,PW]
    const int q = cell_in_b % PW;
    int t = cell_in_b / PW;
    const int p = t % PH;
    const int r = t / PH;

    // Per-lane ROI fetch (the two half-waves may straddle an ROI boundary).
    const f32x4 roi = *(const f32x4*)(rois + (size_t)(b * R + r) * 4);
    const float x1 = roi.x, y1 = roi.y, x2 = roi.z, y2 = roi.w;

    // jnp.round = round-half-to-even -> rintf under default RN mode
    int ws = max((int)rintf(x1), 0);
    int hs = max((int)rintf(y1), 0);
    int we = min((int)rintf(x2), W);
    int he = min((int)rintf(y2), H);

    // TF reshape quirk: out[b,r,p,q,:] = max over h-bin q, w-bin p.
    // Replicate exact fp32 arithmetic of the reference.
    const float hstep = (float)(he - hs) / 7.0f;
    const float wstep = (float)(we - ws) / 7.0f;
    const int hlo = hs + (int)((float)q * hstep);
    const int hhi = (q < PH - 1) ? (hs + (int)((float)(q + 1) * hstep)) : he;
    const int wlo = ws + (int)((float)p * wstep);
    const int whi = (p < PW - 1) ? (ws + (int)((float)(p + 1) * wstep)) : we;

    const int nw = whi - wlo;              // >= 1 (no empty bins by construction)
    const int nh = hhi - hlo;
    const int n  = nh * nw;                // visits for THIS lane's cell

    // Uniform trip count = max over the two half-waves; lanes that finish
    // early freeze their pointer (re-maxing an in-bin value is a no-op).
    const int nmax = max(__builtin_amdgcn_readlane(n, 0),
                         __builtin_amdgcn_readlane(n, 32));

    const int cbase = chalf * 128 + l * 4;   // 4 contiguous channels per lane
    const float* gp = fm + ((size_t)(b * H + hlo) * W + wlo) * C + cbase;
    int gw = 0;
    int left = n;                           // per-lane remaining real visits
    const size_t rstep = (size_t)(W - nw + 1) * C;

    f32x4 acc = { -INFINITY, -INFINITY, -INFINITY, -INFINITY };

#define LOADV(dst) (dst) = *(const f32x4*)gp
#define ADV() { if (left > 1) { --left; \
                  if (++gw == nw) { gw = 0; gp += rstep; } else { gp += (size_t)C; } } }
#define FM(vv) { acc.x = fmaxf(acc.x, (vv).x); acc.y = fmaxf(acc.y, (vv).y); \
                 acc.z = fmaxf(acc.z, (vv).z); acc.w = fmaxf(acc.w, (vv).w); }

    if (nmax >= 8) {
        // 8-deep rotating software pipeline, exactly nmax loads.
        f32x4 v0, v1, v2, v3, v4, v5, v6, v7;
        LOADV(v0); ADV(); LOADV(v1); ADV(); LOADV(v2); ADV(); LOADV(v3); ADV();
        LOADV(v4); ADV(); LOADV(v5); ADV(); LOADV(v6); ADV(); LOADV(v7); ADV();
        int k = nmax - 8;
        while (k >= 8) {
            FM(v0); LOADV(v0); ADV();
            FM(v1); LOADV(v1); ADV();
            FM(v2); LOADV(v2); ADV();
            FM(v3); LOADV(v3); ADV();
            FM(v4); LOADV(v4); ADV();
            FM(v5); LOADV(v5); ADV();
            FM(v6); LOADV(v6); ADV();
            FM(v7); LOADV(v7); ADV();
            k -= 8;
        }
        if (k > 0) { FM(v0); LOADV(v0); ADV(); }
        if (k > 1) { FM(v1); LOADV(v1); ADV(); }
        if (k > 2) { FM(v2); LOADV(v2); ADV(); }
        if (k > 3) { FM(v3); LOADV(v3); ADV(); }
        if (k > 4) { FM(v4); LOADV(v4); ADV(); }
        if (k > 5) { FM(v5); LOADV(v5); ADV(); }
        if (k > 6) { FM(v6); LOADV(v6); ADV(); }
        FM(v0); FM(v1); FM(v2); FM(v3); FM(v4); FM(v5); FM(v6); FM(v7);
    } else if (nmax >= 4) {
        f32x4 v0, v1, v2, v3;
        LOADV(v0); ADV(); LOADV(v1); ADV(); LOADV(v2); ADV(); LOADV(v3); ADV();
        int k = nmax - 4;
        if (k > 0) { FM(v0); LOADV(v0); ADV(); }
        if (k > 1) { FM(v1); LOADV(v1); ADV(); }
        if (k > 2) { FM(v2); LOADV(v2); ADV(); }
        FM(v0); FM(v1); FM(v2); FM(v3);
    } else {
        for (int i = 0; i < nmax; ++i) {
            f32x4 v; LOADV(v); ADV(); FM(v);
        }
    }

    // Non-temporal store: out is write-once; keep it from evicting the fm
    // channel-half slice out of the per-XCD L2.
    const int cell = ((b * R + r) * PH + p) * PW + q;
    float* op = out + (size_t)cell * C + cbase;
    __builtin_nontemporal_store(acc, (f32x4*)op);
}

extern "C" void kernel_launch(void* const* d_in, const int* in_sizes, int n_in,
                              void* d_out, int out_size, void* d_ws, size_t ws_size,
                              hipStream_t stream) {
    const float* fm   = (const float*)d_in[0];
    const float* rois = (const float*)d_in[1];
    float* out = (float*)d_out;

    roi_pool_kernel<<<BLOCKS_TOTAL, 256, 0, stream>>>(fm, rois, out);
}